// Round 9
// baseline (222.079 us; speedup 1.0000x reference)
//
#include <hip/hip_runtime.h>

// LogSig rolling: B=256, NT=4096, D=12, KERNEL=64, STRIDE=16 -> W=253, 78/window.
//
// r6/r7 post-mortem: VGPR_Count pinned at 128 (launch_bounds(.,2) and
// amdgpu_waves_per_eu(2,2) both ignored); acc[66]+streamed rows ~190 live ->
// ~77-92 spilled floats/thread -> 3x WRITE_SIZE, VALUBusy 6-7%, 65-79us.
// Design rule adopted: live set < 128 BY CONSTRUCTION; raise TLP instead.
//
// Geometry: one block per batch (grid=256), 1024 threads = 4 waves/SIMD
// (forced co-residency -> compiler budget exactly 128 VGPR).
//   sub sigma in [0,256): 16-delta span rows 16s..16s+16 (253+3 halo = exactly
//   256 subs; row index clamped at 4095 so sub 255's last delta is 0).
//   Thread t: sigma = t&255, q = t>>8 (WAVE-UNIFORM -> templated pair-slice,
//   no divergence). Each of the 4 q-threads streams the sub's 17 rows
//   (ring-4, lookahead 3, static indices) and accumulates pair slice q of
//   sizes {17,16,17,16}: live = acc(17)+R(48)+c,d(24) ~= 100 < 128.
//   d_k = x_{k+1}-x_k ; acc_p += c_i d_j - c_j d_i ; c += d (c: rel. start).
//   Slices are disjoint -> no combine: q0 writes inc+acc[0,17), q1 [17,33),
//   q2 [33,50), q3 [50,66) + trailing delta to dlt[sigma].
// Phase 2: thread u<253 left-folds S16[u..u+3] by Chen:
//   A += J_acc + I ^ J_inc ; I += J_inc   (J_acc read in 22-float chunks:
//   peak live I12+A66+Jinc12+Ja22 ~= 112). Then removes the trailing delta
//   IN PLACE (I -= dl; A = 0.5*(A - I^dl)) and stores 6+33 float2.

namespace {
constexpr int kB = 256;
constexpr int kNT = 4096;
constexpr int kD = 12;
constexpr int kW = 253;
constexpr int kNPair = 66;
constexpr int kOutC = 78;
constexpr int kThreads = 1024;
constexpr int kSub = 256;
constexpr int kSigStride = 79;           // odd -> 2-way banks (free)
constexpr int kDlStride = 13;
constexpr int kDlBase = kSub * kSigStride;                // 20224 floats
constexpr int kLdsFloats = kDlBase + kSub * kDlStride;    // 23552 floats
constexpr size_t kLdsBytes = (size_t)kLdsFloats * sizeof(float);  // 94208 B
}

__device__ __forceinline__ void load_row(const float* __restrict__ p, float r[kD]) {
    // rows are 48B, 16B-aligned -> 3x float4
    float4 a = *reinterpret_cast<const float4*>(p);
    float4 b = *reinterpret_cast<const float4*>(p + 4);
    float4 c = *reinterpret_cast<const float4*>(p + 8);
    r[0] = a.x; r[1] = a.y; r[2]  = a.z; r[3]  = a.w;
    r[4] = b.x; r[5] = b.y; r[6]  = b.z; r[7]  = b.w;
    r[8] = c.x; r[9] = c.y; r[10] = c.z; r[11] = c.w;
}

// Stream the 16 deltas of sub sigma, accumulating wedge pairs [LO,HI).
template <int LO, int HI, bool WRINC, bool WRDL>
__device__ __forceinline__ void sub_quarter(const float* __restrict__ bb, int sigma,
                                            float* __restrict__ lds) {
    const int r0 = 16 * sigma;
    float R[4][kD];                       // ring, lookahead 3; static &3 indices
#pragma unroll
    for (int r = 0; r < 3; ++r) {
        int g = r0 + r; g = g > kNT - 1 ? kNT - 1 : g;
        load_row(bb + (size_t)g * kD, R[r]);
    }
    float c[kD], d[kD], acc[HI - LO];
#pragma unroll
    for (int z = 0; z < HI - LO; ++z) acc[z] = 0.f;
#pragma unroll
    for (int k = 0; k < 16; ++k) {
        if (k < 14) {                     // load row k+3 into slot holding row k-1
            int g = r0 + k + 3; g = g > kNT - 1 ? kNT - 1 : g;
            load_row(bb + (size_t)g * kD, R[(k + 3) & 3]);
        }
#pragma unroll
        for (int i = 0; i < kD; ++i) d[i] = R[(k + 1) & 3][i] - R[k & 3][i];
        if (k > 0) {                      // k==0 has c==0 -> no wedge
            int p = 0;
#pragma unroll
            for (int i = 0; i < kD; ++i) {
#pragma unroll
                for (int j = i + 1; j < kD; ++j) {
                    if (p >= LO && p < HI)   // folded at unroll time
                        acc[p - LO] = fmaf(c[i], d[j], fmaf(-c[j], d[i], acc[p - LO]));
                    ++p;
                }
            }
        }
#pragma unroll
        for (int i = 0; i < kD; ++i) c[i] = (k == 0) ? d[i] : (c[i] + d[i]);
    }
    float* sigrow = lds + (size_t)sigma * kSigStride;
    if (WRINC) {
#pragma unroll
        for (int i = 0; i < kD; ++i) sigrow[i] = c[i];       // inc = x16 - x0
    }
#pragma unroll
    for (int z = 0; z < HI - LO; ++z) sigrow[kD + LO + z] = acc[z];
    if (WRDL) {
        float* dd = lds + kDlBase + (size_t)sigma * kDlStride;
#pragma unroll
        for (int i = 0; i < kD; ++i) dd[i] = d[i];           // trailing delta
    }
}

__global__ __launch_bounds__(kThreads, 1)
void logsig_q4(const float* __restrict__ inp, float* __restrict__ out) {
    extern __shared__ float lds[];
    const int b = blockIdx.x;
    const int t = threadIdx.x;
    const int sigma = t & 255;
    const int q = t >> 8;                 // wave-uniform (256 % 64 == 0)
    const float* bb = inp + (size_t)b * kNT * kD;

    switch (q) {                          // uniform branch, no divergence
    case 0:  sub_quarter< 0, 17, true,  false>(bb, sigma, lds); break;
    case 1:  sub_quarter<17, 33, false, false>(bb, sigma, lds); break;
    case 2:  sub_quarter<33, 50, false, false>(bb, sigma, lds); break;
    default: sub_quarter<50, 66, false, true >(bb, sigma, lds); break;
    }

    __syncthreads();

    // ---------------- Phase 2: fold 4 subs per window + tail removal ---------
    if (t < kW) {
        const int u = t;
        float I[kD], A[kNPair];
        {
            const float* s0 = lds + (size_t)u * kSigStride;
#pragma unroll
            for (int i = 0; i < kD; ++i) I[i] = s0[i];
#pragma unroll
            for (int p = 0; p < kNPair; ++p) A[p] = s0[kD + p];
        }
#pragma unroll
        for (int r = 1; r < 4; ++r) {
            const float* src = lds + (size_t)(u + r) * kSigStride;
            float Jinc[kD];
#pragma unroll
            for (int i = 0; i < kD; ++i) Jinc[i] = src[i];
#pragma unroll
            for (int ch = 0; ch < 3; ++ch) {         // J_acc in 22-float chunks
                float Ja[22];
#pragma unroll
                for (int z = 0; z < 22; ++z) Ja[z] = src[kD + ch * 22 + z];
                int p = 0;
#pragma unroll
                for (int i = 0; i < kD; ++i) {
#pragma unroll
                    for (int j = i + 1; j < kD; ++j) {
                        if (p >= ch * 22 && p < ch * 22 + 22) {  // folded
                            float a = A[p] + Ja[p - ch * 22];    // accL + accR
                            a = fmaf(I[i], Jinc[j], a);          // + I_i J_j
                            a = fmaf(-I[j], Jinc[i], a);         // - I_j J_i
                            A[p] = a;
                        }
                        ++p;
                    }
                }
            }
#pragma unroll
            for (int i = 0; i < kD; ++i) I[i] += Jinc[i];        // after cross
        }

        // tail removal in place: I_Q = I - dl ; A = 0.5*(A - I_Q ^ dl)
        float dl[kD];
        {
            const float* dd = lds + kDlBase + (size_t)(u + 3) * kDlStride;
#pragma unroll
            for (int i = 0; i < kD; ++i) dl[i] = dd[i];
        }
#pragma unroll
        for (int i = 0; i < kD; ++i) I[i] -= dl[i];              // I = lvl1
        {
            int p = 0;
#pragma unroll
            for (int i = 0; i < kD; ++i) {
#pragma unroll
                for (int j = i + 1; j < kD; ++j) {
                    A[p] = 0.5f * fmaf(I[j], dl[i], fmaf(-I[i], dl[j], A[p]));
                    ++p;
                }
            }
        }

        // out row: 12 lvl1 + 66 areas = 6 + 33 float2 (312B, 8-aligned)
        float2* o = reinterpret_cast<float2*>(out + ((size_t)b * kW + u) * kOutC);
#pragma unroll
        for (int z = 0; z < 6; ++z)
            o[z] = make_float2(I[2 * z], I[2 * z + 1]);
#pragma unroll
        for (int z = 0; z < 33; ++z)
            o[6 + z] = make_float2(A[2 * z], A[2 * z + 1]);
    }
}

extern "C" void kernel_launch(void* const* d_in, const int* in_sizes, int n_in,
                              void* d_out, int out_size, void* d_ws, size_t ws_size,
                              hipStream_t stream) {
    const float* inp = (const float*)d_in[0];
    float* out = (float*)d_out;
    // >64KB dynamic LDS: declare cap every call (idempotent, capture-safe)
    (void)hipFuncSetAttribute((const void*)logsig_q4,
                              hipFuncAttributeMaxDynamicSharedMemorySize,
                              (int)kLdsBytes);
    logsig_q4<<<kB, kThreads, kLdsBytes, stream>>>(inp, out);
}

// Round 13
// 109.332 us; speedup vs baseline: 2.0312x; 2.0312x over previous
//
#include <hip/hip_runtime.h>

// LogSig rolling: B=256, NT=4096, D=12, KERNEL=64, STRIDE=16 -> W=253, 78/window.
//
// Allocator law (measured r6/r7/r9): VGPR budget = f(block size), immovable by
// launch_bounds/waves_per_eu attrs: 512 thr -> 128 VGPR, 1024 thr -> 64 VGPR.
// r9 (1024 thr, live ~100 vs budget 64) churned scratch: WRITE 182MB, FETCH
// 340MB, 156us. Rule: 512 threads + live set <= ~118 BY CONSTRUCTION.
//
// Geometry: one block per batch (grid=256), 512 threads, 2 threads per
// 16-delta sub (256 subs = 253 windows + 3 halo, exact fit).
//   WAVE-UNIFORM role split (r10 audit: half=t&1 diverged inside the wave,
//   serializing both template bodies): sigma = (t>>7)*64 + (t&63),
//   half = (t>>6)&1 -> waves 0,2,4,6 do half0, waves 1,3,5,7 do half1.
//   sub sigma spans rows 16s..16s+16 (clamped at 4095: sub 255's last delta
//   is 0, which makes window 252's 63-delta range fall out exactly).
//   Each half accumulates a DISJOINT 33-pair slice of the wedge (no combine
//   needed) while streaming 17 rows through a ring-4 (lookahead 3, static
//   indices; r11 audit: prefetch bound is k<14 so row 16 IS loaded -- k<13
//   left R[0] holding stale row 12 at the last delta): live = acc33 + R48 +
//   c,d 24 + addr ~= 115 < 128.
//   d_k = x_{k+1}-x_k ; acc_p += c_i d_j - c_j d_i ; c += d.
//   half0 writes [inc12, acc 0..33); half1 writes acc[33..66) + trailing
//   delta d to dlt[sigma].
// Phase 2: thread u<253 left-folds S16[u..u+3] by Chen:
//   A += J_acc + I ^ J_inc ; I += J_inc  (J_acc in 11-float chunks, peak ~110)
//   then tail removal in place: I -= dl ; A = 0.5*(A - I ^ dl); direct float2
//   stores (wave writes 64 consecutive 312B rows = 19.9KB contiguous).

namespace {
constexpr int kB = 256;
constexpr int kNT = 4096;
constexpr int kD = 12;
constexpr int kW = 253;
constexpr int kNPair = 66;
constexpr int kOutC = 78;
constexpr int kThreads = 512;
constexpr int kSub = 256;
constexpr int kSigStride = 79;           // odd -> 2-way banks (free)
constexpr int kDlStride = 13;
constexpr int kDlBase = kSub * kSigStride;                // 20224 floats
constexpr int kLdsFloats = kDlBase + kSub * kDlStride;    // 23552 floats
constexpr size_t kLdsBytes = (size_t)kLdsFloats * sizeof(float);  // 94208 B
}

__device__ __forceinline__ void load_row(const float* __restrict__ p, float r[kD]) {
    // rows are 48B, 16B-aligned -> 3x float4
    float4 a = *reinterpret_cast<const float4*>(p);
    float4 b = *reinterpret_cast<const float4*>(p + 4);
    float4 c = *reinterpret_cast<const float4*>(p + 8);
    r[0] = a.x; r[1] = a.y; r[2]  = a.z; r[3]  = a.w;
    r[4] = b.x; r[5] = b.y; r[6]  = b.z; r[7]  = b.w;
    r[8] = c.x; r[9] = c.y; r[10] = c.z; r[11] = c.w;
}

// Stream the 16 deltas of sub sigma, accumulating wedge pairs [LO,HI).
// Ring-4 row buffer, lookahead 3, all indices compile-time (full unroll).
// Slot reuse proof: row k+3 overwrites slot (k+3)&3 which holds row k-1,
// last read at step k-1 (d = R[k]-R[k-1]); k=13 loads row 16 into R[0]
// (row 12's slot, last read at step 12).
template <int LO, int HI, bool WRINC, bool WRDL>
__device__ __forceinline__ void sub_half(const float* __restrict__ bb, int sigma,
                                         float* __restrict__ lds) {
    const int r0 = 16 * sigma;
    float R[4][kD];
#pragma unroll
    for (int r = 0; r < 3; ++r) {
        int g = r0 + r; g = g > kNT - 1 ? kNT - 1 : g;
        load_row(bb + (size_t)g * kD, R[r]);
    }
    float c[kD], d[kD], acc[HI - LO];
#pragma unroll
    for (int z = 0; z < HI - LO; ++z) acc[z] = 0.f;
#pragma unroll
    for (int k = 0; k < 16; ++k) {
        if (k < 14) {                     // rows 3..16 (k=13 -> row 16)
            int g = r0 + k + 3; g = g > kNT - 1 ? kNT - 1 : g;
            load_row(bb + (size_t)g * kD, R[(k + 3) & 3]);
        }
#pragma unroll
        for (int i = 0; i < kD; ++i) d[i] = R[(k + 1) & 3][i] - R[k & 3][i];
        if (k > 0) {                      // k==0 has c==0 -> no wedge
            int p = 0;
#pragma unroll
            for (int i = 0; i < kD; ++i) {
#pragma unroll
                for (int j = i + 1; j < kD; ++j) {
                    if (p >= LO && p < HI)   // folded at unroll time
                        acc[p - LO] = fmaf(c[i], d[j], fmaf(-c[j], d[i], acc[p - LO]));
                    ++p;
                }
            }
        }
#pragma unroll
        for (int i = 0; i < kD; ++i) c[i] = (k == 0) ? d[i] : (c[i] + d[i]);
    }
    float* sigrow = lds + (size_t)sigma * kSigStride;
    if (WRINC) {
#pragma unroll
        for (int i = 0; i < kD; ++i) sigrow[i] = c[i];       // inc = x16 - x0
    }
#pragma unroll
    for (int z = 0; z < HI - LO; ++z) sigrow[kD + LO + z] = acc[z];
    if (WRDL) {
        float* dd = lds + kDlBase + (size_t)sigma * kDlStride;
#pragma unroll
        for (int i = 0; i < kD; ++i) dd[i] = d[i];           // trailing delta
    }
}

__global__ __launch_bounds__(kThreads)
void logsig_h2u(const float* __restrict__ inp, float* __restrict__ out) {
    extern __shared__ float lds[];
    const int b = blockIdx.x;
    const int t = threadIdx.x;
    const int sigma = ((t >> 7) << 6) | (t & 63);   // 4 groups of 64 subs
    const int half = (t >> 6) & 1;                  // wave-uniform role
    const float* bb = inp + (size_t)b * kNT * kD;

    if (half == 0)
        sub_half<0, 33, true, false>(bb, sigma, lds);
    else
        sub_half<33, 66, false, true>(bb, sigma, lds);

    __syncthreads();

    // ---------------- Phase 2: fold 4 subs per window + tail removal ---------
    if (t < kW) {
        const int u = t;
        float I[kD], A[kNPair];
        {
            const float* s0 = lds + (size_t)u * kSigStride;
#pragma unroll
            for (int i = 0; i < kD; ++i) I[i] = s0[i];
#pragma unroll
            for (int p = 0; p < kNPair; ++p) A[p] = s0[kD + p];
        }
#pragma unroll
        for (int r = 1; r < 4; ++r) {
            const float* src = lds + (size_t)(u + r) * kSigStride;
            float Jinc[kD];
#pragma unroll
            for (int i = 0; i < kD; ++i) Jinc[i] = src[i];
#pragma unroll
            for (int ch = 0; ch < 6; ++ch) {         // J_acc in 11-float chunks
                float Ja[11];
#pragma unroll
                for (int z = 0; z < 11; ++z) Ja[z] = src[kD + ch * 11 + z];
                int p = 0;
#pragma unroll
                for (int i = 0; i < kD; ++i) {
#pragma unroll
                    for (int j = i + 1; j < kD; ++j) {
                        if (p >= ch * 11 && p < ch * 11 + 11) {  // folded
                            float a = A[p] + Ja[p - ch * 11];    // accL + accR
                            a = fmaf(I[i], Jinc[j], a);          // + I_i J_j
                            a = fmaf(-I[j], Jinc[i], a);         // - I_j J_i
                            A[p] = a;
                        }
                        ++p;
                    }
                }
            }
#pragma unroll
            for (int i = 0; i < kD; ++i) I[i] += Jinc[i];        // after cross
        }

        // tail removal in place: I -= dl ; A = 0.5*(A - I ^ dl)
        float dl[kD];
        {
            const float* dd = lds + kDlBase + (size_t)(u + 3) * kDlStride;
#pragma unroll
            for (int i = 0; i < kD; ++i) dl[i] = dd[i];
        }
#pragma unroll
        for (int i = 0; i < kD; ++i) I[i] -= dl[i];              // I = lvl1
        {
            int p = 0;
#pragma unroll
            for (int i = 0; i < kD; ++i) {
#pragma unroll
                for (int j = i + 1; j < kD; ++j) {
                    A[p] = 0.5f * fmaf(I[j], dl[i], fmaf(-I[i], dl[j], A[p]));
                    ++p;
                }
            }
        }

        // out row: 12 lvl1 + 66 areas = 6 + 33 float2 (312B, 8-aligned)
        float2* o = reinterpret_cast<float2*>(out + ((size_t)b * kW + u) * kOutC);
#pragma unroll
        for (int z = 0; z < 6; ++z)
            o[z] = make_float2(I[2 * z], I[2 * z + 1]);
#pragma unroll
        for (int z = 0; z < 33; ++z)
            o[6 + z] = make_float2(A[2 * z], A[2 * z + 1]);
    }
}

extern "C" void kernel_launch(void* const* d_in, const int* in_sizes, int n_in,
                              void* d_out, int out_size, void* d_ws, size_t ws_size,
                              hipStream_t stream) {
    const float* inp = (const float*)d_in[0];
    float* out = (float*)d_out;
    // >64KB dynamic LDS: declare cap every call (idempotent, capture-safe)
    (void)hipFuncSetAttribute((const void*)logsig_h2u,
                              hipFuncAttributeMaxDynamicSharedMemorySize,
                              (int)kLdsBytes);
    logsig_h2u<<<kB, kThreads, kLdsBytes, stream>>>(inp, out);
}